// Round 1
// baseline (1066.375 us; speedup 1.0000x reference)
//
#include <hip/hip_runtime.h>
#include <stdint.h>

// MemoryModule: z[N=65536,D=256], memory[M=2000,D=256] (fp32)
//   z_norm, m_norm = row-L2-normalize (eps added to norm)
//   sim = z_norm @ m_norm^T   [N,M]
//   w = softmax(sim, axis=1)
//   w2 = relu(w-lamb)*w/(|w-lamb|+1e-12); w_hat = w2/(sum w2 + 1e-12)
//   z_hat = w_hat @ memory    [N,D]
// d_out = [z_hat (N*D) | w_hat (N*M)] fp32

typedef float  f32x4  __attribute__((ext_vector_type(4)));
typedef __bf16 bf16x8 __attribute__((ext_vector_type(8)));

#define DDIM 256
#define MDIM 2000
#define MT   125          // 2000 / 16 m-tiles
#define MPAD 2048
#define LAMB 0.002f
#define EPS_NORM 1e-10f
#define EPS_SHRINK 1e-12f

// ---------------- kernel 1: memory -> bf16 m_norm (padded to MPAD rows) ----
__global__ __launch_bounds__(256) void norm_mem_k(const float* __restrict__ mem,
                                                  __bf16* __restrict__ mnorm) {
  const int row = blockIdx.x;
  const int t   = threadIdx.x;
  if (row >= MDIM) { mnorm[(size_t)row * DDIM + t] = (__bf16)0.0f; return; }
  float x = mem[(size_t)row * DDIM + t];
  float s = x * x;
  #pragma unroll
  for (int m = 1; m < 64; m <<= 1) s += __shfl_xor(s, m, 64);
  __shared__ float wsum[4];
  if ((t & 63) == 0) wsum[t >> 6] = s;
  __syncthreads();
  s = wsum[0] + wsum[1] + wsum[2] + wsum[3];
  const float scale = 1.0f / (sqrtf(s) + EPS_NORM);
  mnorm[(size_t)row * DDIM + t] = (__bf16)(x * scale);
}

// ---------------- kernel 2: fused per-16-row block ------------------------
// block = 256 threads (4 waves). Each block owns 16 z-rows.
// Waves split 128 m-tiles (125 valid) round-robin: tile t = wave + 4*i.
// sim tile kept in registers: 32 x f32x4 per lane (MFMA C layout:
// col = lane&15 (m within tile), row = (lane>>4)*4 + reg (n within 16)).
__global__ __launch_bounds__(256, 2) void fused_k(
    const float* __restrict__ z, const __bf16* __restrict__ mnorm,
    const float* __restrict__ mem, float* __restrict__ outz,
    float* __restrict__ outw) {
  __shared__ __bf16 zs[16][264];   // +8 bf16 pad per row: spreads b128 banks
  __shared__ float  red[4][16];
  __shared__ float  zacc[16][DDIM];
  __shared__ int    anyflag;

  const int tid  = threadIdx.x;
  const int n0   = blockIdx.x * 16;
  const int lane = tid & 63;
  const int wave = tid >> 6;
  const int quad = lane >> 4;
  const int col  = lane & 15;

  if (tid == 0) anyflag = 0;

  // ---- phase 1: z_norm -> zs (bf16). thread = (row tid>>4, 16 cols) ----
  {
    const int r  = tid >> 4;
    const int c0 = (tid & 15) * 16;
    const float* zp = z + (size_t)(n0 + r) * DDIM + c0;
    float v[16];
    #pragma unroll
    for (int k = 0; k < 4; ++k) {
      const float4 q = *(const float4*)(zp + 4 * k);
      v[4*k+0] = q.x; v[4*k+1] = q.y; v[4*k+2] = q.z; v[4*k+3] = q.w;
    }
    float s = 0.f;
    #pragma unroll
    for (int k = 0; k < 16; ++k) s += v[k] * v[k];
    #pragma unroll
    for (int m = 1; m < 16; m <<= 1) s += __shfl_xor(s, m, 64);
    const float scale = 1.0f / (sqrtf(s) + EPS_NORM);
    #pragma unroll
    for (int k = 0; k < 16; ++k) zs[r][c0 + k] = (__bf16)(v[k] * scale);
  }
  __syncthreads();

  // ---- phase 2: A-fragments (z side) from LDS, then MFMA over m-tiles ----
  // A[m=lane&15][k=quad*8+j] per 16x16x32 step; K=256 -> 8 chunks.
  bf16x8 af[8];
  #pragma unroll
  for (int kc = 0; kc < 8; ++kc)
    af[kc] = *(const bf16x8*)&zs[col][kc * 32 + quad * 8];

  f32x4 acc[32];
  #pragma unroll
  for (int i = 0; i < 32; ++i) acc[i] = (f32x4){0.f, 0.f, 0.f, 0.f};

  #pragma unroll
  for (int i = 0; i < 32; ++i) {
    const int t = wave + 4 * i;
    if (t < MT) {
      const __bf16* bp = mnorm + (size_t)(t * 16 + col) * DDIM + quad * 8;
      f32x4 c = acc[i];
      #pragma unroll
      for (int kc = 0; kc < 8; ++kc) {
        const bf16x8 b = *(const bf16x8*)(bp + kc * 32);
        c = __builtin_amdgcn_mfma_f32_16x16x32_bf16(af[kc], b, c, 0, 0, 0);
      }
      acc[i] = c;
    }
  }

  // ---- phase 3a: row max ----
  float rmax[4];
  {
    float lm[4];
    #pragma unroll
    for (int j = 0; j < 4; ++j) lm[j] = -1e30f;
    #pragma unroll
    for (int i = 0; i < 32; ++i) {
      const int t = wave + 4 * i;
      if (t < MT) {
        #pragma unroll
        for (int j = 0; j < 4; ++j) lm[j] = fmaxf(lm[j], acc[i][j]);
      }
    }
    #pragma unroll
    for (int j = 0; j < 4; ++j) {
      #pragma unroll
      for (int m = 1; m < 16; m <<= 1) lm[j] = fmaxf(lm[j], __shfl_xor(lm[j], m, 64));
    }
    if (col == 0) {
      #pragma unroll
      for (int j = 0; j < 4; ++j) red[wave][quad * 4 + j] = lm[j];
    }
    __syncthreads();
    #pragma unroll
    for (int j = 0; j < 4; ++j) {
      const int r = quad * 4 + j;
      rmax[j] = fmaxf(fmaxf(red[0][r], red[1][r]), fmaxf(red[2][r], red[3][r]));
    }
    __syncthreads();
  }

  // ---- phase 3b: exp + row sum (overwrite acc with exp values) ----
  float rsum[4];
  {
    float ls[4] = {0.f, 0.f, 0.f, 0.f};
    #pragma unroll
    for (int i = 0; i < 32; ++i) {
      const int t = wave + 4 * i;
      if (t < MT) {
        #pragma unroll
        for (int j = 0; j < 4; ++j) {
          const float e = __expf(acc[i][j] - rmax[j]);
          acc[i][j] = e;
          ls[j] += e;
        }
      }
    }
    #pragma unroll
    for (int j = 0; j < 4; ++j) {
      #pragma unroll
      for (int m = 1; m < 16; m <<= 1) ls[j] += __shfl_xor(ls[j], m, 64);
    }
    if (col == 0) {
      #pragma unroll
      for (int j = 0; j < 4; ++j) red[wave][quad * 4 + j] = ls[j];
    }
    __syncthreads();
    #pragma unroll
    for (int j = 0; j < 4; ++j) {
      const int r = quad * 4 + j;
      rsum[j] = red[0][r] + red[1][r] + red[2][r] + red[3][r];
    }
    __syncthreads();
  }

  // ---- phase 3c: w, hard-shrink, shrink-sum (overwrite acc with w2) ----
  float rs2[4];
  {
    float inv[4];
    #pragma unroll
    for (int j = 0; j < 4; ++j) inv[j] = 1.0f / rsum[j];
    float ls[4] = {0.f, 0.f, 0.f, 0.f};
    #pragma unroll
    for (int i = 0; i < 32; ++i) {
      const int t = wave + 4 * i;
      if (t < MT) {
        #pragma unroll
        for (int j = 0; j < 4; ++j) {
          const float w = acc[i][j] * inv[j];
          const float d = w - LAMB;
          float w2 = 0.f;
          if (d > 0.f) { w2 = d * w / (d + EPS_SHRINK); anyflag = 1; }
          acc[i][j] = w2;
          ls[j] += w2;
        }
      }
    }
    #pragma unroll
    for (int j = 0; j < 4; ++j) {
      #pragma unroll
      for (int m = 1; m < 16; m <<= 1) ls[j] += __shfl_xor(ls[j], m, 64);
    }
    if (col == 0) {
      #pragma unroll
      for (int j = 0; j < 4; ++j) red[wave][quad * 4 + j] = ls[j];
    }
    __syncthreads();
    #pragma unroll
    for (int j = 0; j < 4; ++j) {
      const int r = quad * 4 + j;
      rs2[j] = red[0][r] + red[1][r] + red[2][r] + red[3][r];
    }
  }

  // ---- phase 3d: w_hat = w2/(s2+eps), write out (acc keeps w_hat) ----
  #pragma unroll
  for (int j = 0; j < 4; ++j) rs2[j] = 1.0f / (rs2[j] + EPS_SHRINK);
  #pragma unroll
  for (int i = 0; i < 32; ++i) {
    const int t = wave + 4 * i;
    if (t < MT) {
      #pragma unroll
      for (int j = 0; j < 4; ++j) {
        const float wh = acc[i][j] * rs2[j];
        acc[i][j] = wh;
        outw[(size_t)(n0 + quad * 4 + j) * MDIM + (size_t)t * 16 + col] = wh;
      }
    }
  }

  __syncthreads();   // anyflag + red reads complete

  // ---- phase 4: z_hat. Sparse path only if any weight survived. ----
  if (anyflag == 0) {
    const float4 z4 = {0.f, 0.f, 0.f, 0.f};
    float4* oz = (float4*)(outz + (size_t)n0 * DDIM);
    #pragma unroll
    for (int k = 0; k < 4; ++k) oz[tid + 256 * k] = z4;
  } else {
    for (int idx = tid; idx < 16 * DDIM; idx += 256) ((float*)zacc)[idx] = 0.f;
    __syncthreads();
    #pragma unroll
    for (int i = 0; i < 32; ++i) {
      const int t = wave + 4 * i;
      if (t < MT) {
        #pragma unroll
        for (int j = 0; j < 4; ++j) {
          const float wh = acc[i][j];
          if (wh > 0.f) {
            const float* mrow = mem + (size_t)(t * 16 + col) * DDIM;
            float* zr = &zacc[quad * 4 + j][0];
            for (int dd = 0; dd < DDIM; ++dd) atomicAdd(&zr[dd], wh * mrow[dd]);
          }
        }
      }
    }
    __syncthreads();
    const int r  = tid >> 4;
    const int c0 = (tid & 15) * 16;
    #pragma unroll
    for (int k = 0; k < 4; ++k)
      *(float4*)(outz + (size_t)(n0 + r) * DDIM + c0 + 4 * k) =
          *(float4*)&zacc[r][c0 + 4 * k];
  }
}

extern "C" void kernel_launch(void* const* d_in, const int* in_sizes, int n_in,
                              void* d_out, int out_size, void* d_ws, size_t ws_size,
                              hipStream_t stream) {
  const float* z   = (const float*)d_in[0];
  const float* mem = (const float*)d_in[1];
  const int N = in_sizes[0] / DDIM;           // 65536
  float* outz = (float*)d_out;                // [N, D]
  float* outw = outz + (size_t)N * DDIM;      // [N, M]
  __bf16* mnorm = (__bf16*)d_ws;              // [MPAD, D] bf16 = 1 MiB

  hipLaunchKernelGGL(norm_mem_k, dim3(MPAD), dim3(DDIM), 0, stream, mem, mnorm);
  hipLaunchKernelGGL(fused_k, dim3(N / 16), dim3(256), 0, stream,
                     z, mnorm, mem, outz, outw);
}